// Round 11
// baseline (502.583 us; speedup 1.0000x reference)
//
#include <hip/hip_runtime.h>
#include <hip/hip_bf16.h>

#define NUM_USERS 100000
#define NUM_ITEMS 50000
#define EMBED_DIM 64
#define N_NODES   150000                 // NUM_USERS + NUM_ITEMS
#define ROW_SHIFT 9                      // 512 rows per bucket
#define ROWS_PER_BUCKET 512
#define B_BUCKETS ((N_NODES + ROWS_PER_BUCKET - 1) / ROWS_PER_BUCKET)   // 293
#define NBP 512                          // padded bucket-array size
#define BIN_CHUNK 2048                   // edges per bin block (4/thread @512)
#define PLACE_CHUNK 2048                 // staging entries per hist/place block
#define COL_MASK 0x3FFFF                 // 18 bits for col (N_NODES < 262144)

typedef unsigned short ushort_t;
typedef unsigned int uint_t;
typedef __attribute__((ext_vector_type(16))) int i16;

__device__ __forceinline__ float bf16_to_f32(ushort_t u) {
    return __uint_as_float(((unsigned)u) << 16);
}
__device__ __forceinline__ ushort_t f32_to_bf16(float f) {
    return __builtin_bit_cast(ushort_t, __float2bfloat16(f));   // RNE
}

// 512-thread (8-wave) exclusive scan via shfl_up: 2 barriers.
__device__ __forceinline__ void scan512(int c, int t, int* wsum,
                                        int* excl_out, int* total_out) {
    int lane = t & 63, wv = t >> 6;
    int x = c;
#pragma unroll
    for (int d = 1; d < 64; d <<= 1) {
        int y = __shfl_up(x, d, 64);
        if (lane >= d) x += y;
    }
    if (lane == 63) wsum[wv] = x;
    __syncthreads();
    if (t < 64) {
        int s = (lane < 8) ? wsum[lane] : 0;
#pragma unroll
        for (int d = 1; d < 8; d <<= 1) {
            int y = __shfl_up(s, d, 64);
            if (lane >= d) s += y;
        }
        if (lane < 8) wsum[lane] = s;
    }
    __syncthreads();
    int off = (wv > 0) ? wsum[wv - 1] : 0;
    *excl_out = x + off - c;
    *total_out = wsum[7];
}

// ---------------------------------------------------------------------------
// k_bin2 (UNCHANGED from R20): LDS-only atomics; heterogeneous grid
// (convert + bin). 2-barrier shfl scan; cols/vals register-carried from
// pass 1. R18 LESSON kept: no per-edge global atomics anywhere.
// ---------------------------------------------------------------------------
__global__ void __launch_bounds__(512) k_bin2(const float* __restrict__ ue,
                                              const float* __restrict__ ie,
                                              ushort_t* __restrict__ xb,
                                              const int* __restrict__ rows,
                                              const int* __restrict__ cols,
                                              const float* __restrict__ vals,
                                              int* __restrict__ cursor,
                                              int2* __restrict__ staging,
                                              int nnz, int cap, int g_conv) {
    int t = threadIdx.x;
    if ((int)blockIdx.x < g_conv) {
        // ---- convert: fp32 ego table -> bf16 (float4 granularity) ----
        int i = blockIdx.x * 512 + t;
        const int n4 = (N_NODES * EMBED_DIM) / 4;
        if (i >= n4) return;
        const int usplit = (NUM_USERS * EMBED_DIM) / 4;
        float4 f = (i < usplit) ? ((const float4*)ue)[i] : ((const float4*)ie)[i - usplit];
        ushort4 o;
        o.x = f32_to_bf16(f.x);
        o.y = f32_to_bf16(f.y);
        o.z = f32_to_bf16(f.z);
        o.w = f32_to_bf16(f.w);
        ((ushort4*)xb)[i] = o;
        return;
    }

    // ---- binning ----
    __shared__ int  ccnt[NBP];
    __shared__ int  cpos[NBP];
    __shared__ int  gdst[NBP];
    __shared__ int  wsum[8];
    __shared__ int2 entries[BIN_CHUNK];            // 16 KB
    __shared__ ushort_t ebuck[BIN_CHUNK];          // 4 KB

    int base = (blockIdx.x - g_conv) * BIN_CHUNK;
    ccnt[t] = 0;
    __syncthreads();

    int   myrow[BIN_CHUNK / 512];
    int   mycol[BIN_CHUNK / 512];
    float myval[BIN_CHUNK / 512];
#pragma unroll
    for (int k = 0; k < BIN_CHUNK / 512; k++) {
        int idx = base + k * 512 + t;
        int r = (idx < nnz) ? rows[idx] : -1;
        myrow[k] = r;
        if (r >= 0) {
            mycol[k] = cols[idx];
            myval[k] = vals[idx];
            atomicAdd(&ccnt[r >> ROW_SHIFT], 1);
        }
    }
    __syncthreads();

    int c = ccnt[t];
    int excl, total;
    scan512(c, t, wsum, &excl, &total);            // 2 barriers
    cpos[t] = excl;
    __syncthreads();

#pragma unroll
    for (int k = 0; k < BIN_CHUNK / 512; k++) {
        int r = myrow[k];
        if (r >= 0) {
            int b = r >> ROW_SHIFT;
            int lrow = r & (ROWS_PER_BUCKET - 1);
            int slot = atomicAdd(&cpos[b], 1);
            entries[slot] = make_int2(mycol[k] | (lrow << 18), __float_as_int(myval[k]));
            ebuck[slot] = (ushort_t)b;
        }
    }
    __syncthreads();

    // reserve space in each touched bucket's fixed region
    if (t < B_BUCKETS && ccnt[t] > 0) {
        int g = atomicAdd(&cursor[t], ccnt[t]);
        gdst[t] = t * cap + g - (cpos[t] - ccnt[t]);
    }
    __syncthreads();

    for (int i = t; i < total; i += 512) {
        int eb = ebuck[i];
        int pos = gdst[eb] + i;
        if (pos < (eb + 1) * cap)                     // capacity guard (never hits)
            staging[pos] = entries[i];
    }
}

// ---------------------------------------------------------------------------
// k_hist (UNCHANGED): per-(bucket,chunk) row histogram into private H slot.
// ---------------------------------------------------------------------------
__global__ void __launch_bounds__(512) k_hist(const int2* __restrict__ staging,
                                              const int* __restrict__ cursor,
                                              int* __restrict__ H,
                                              int cap, int chunks) {
    __shared__ int h[ROWS_PER_BUCKET];
    int b = blockIdx.x / chunks;
    int k = blockIdx.x - b * chunks;
    int t = threadIdx.x;
    h[t] = 0;
    __syncthreads();
    int cnt_b = cursor[b];
    if (cnt_b > cap) cnt_b = cap;
    int hi = k * PLACE_CHUNK + PLACE_CHUNK;
    if (hi > cnt_b) hi = cnt_b;
    int rbase = b * cap;
#pragma unroll 1
    for (int i = k * PLACE_CHUNK + t; i < hi; i += 512)
        atomicAdd(&h[staging[rbase + i].x >> 18], 1);
    __syncthreads();
    H[(size_t)blockIdx.x * ROWS_PER_BUCKET + t] = h[t];
}

// ---------------------------------------------------------------------------
// k_scan2 (UNCHANGED): per-bucket scan of H -> ranges + per-(chunk,row)
// start cursors rewritten into H.
// ---------------------------------------------------------------------------
__global__ void __launch_bounds__(512) k_scan2(int* __restrict__ H,
                                               int2* __restrict__ ranges,
                                               int cap, int chunks) {
    __shared__ int wsum[8];
    int b = blockIdx.x;
    int t = threadIdx.x;
    size_t base = (size_t)b * chunks * ROWS_PER_BUCKET + t;
    int c = 0;
#pragma unroll 1
    for (int k = 0; k < chunks; k++) c += H[base + (size_t)k * ROWS_PER_BUCKET];
    int excl, total;
    scan512(c, t, wsum, &excl, &total);
    (void)total;
    int row = (b << ROW_SHIFT) + t;
    int beg = b * cap + excl;
    if (row < N_NODES) ranges[row] = make_int2(beg, beg + c);
    int s = beg;
#pragma unroll 1
    for (int k = 0; k < chunks; k++) {
        int hh = H[base + (size_t)k * ROWS_PER_BUCKET];
        H[base + (size_t)k * ROWS_PER_BUCKET] = s;
        s += hh;
    }
}

// ---------------------------------------------------------------------------
// k_place2 (UNCHANGED from R21 intent: writes SPLIT cvc/cvv so the SpMM can
// s_load vals into SGPRs). LDS cursors; writes confined to per-bucket
// windows -> L2-merged.
// ---------------------------------------------------------------------------
__global__ void __launch_bounds__(512) k_place2(const int2* __restrict__ staging,
                                                const int* __restrict__ cursor,
                                                const int* __restrict__ H,
                                                int* __restrict__ cvc,
                                                float* __restrict__ cvv,
                                                int cap, int chunks) {
    __shared__ int c[ROWS_PER_BUCKET];
    int b = blockIdx.x / chunks;
    int k = blockIdx.x - b * chunks;
    int t = threadIdx.x;
    c[t] = H[(size_t)blockIdx.x * ROWS_PER_BUCKET + t];
    __syncthreads();
    int cnt_b = cursor[b];
    if (cnt_b > cap) cnt_b = cap;
    int hi = k * PLACE_CHUNK + PLACE_CHUNK;
    if (hi > cnt_b) hi = cnt_b;
    int rbase = b * cap;
#pragma unroll 1
    for (int i = k * PLACE_CHUNK + t; i < hi; i += 512) {
        int2 e = staging[rbase + i];
        int pos = atomicAdd(&c[e.x >> 18], 1);
        cvc[pos] = e.x & COL_MASK;
        cvv[pos] = __int_as_float(e.y);
    }
}

// ---------------------------------------------------------------------------
// R21b SpMM row body. Same as R21 with the COMPILE FIX: the s_load base is
// reconstructed from two readfirstlane'd halves, guaranteeing LLVM sees a
// uniform (SGPR) value for the "s" constraint. (R21's failure: k_last's
// divergent beg/end phi made `cvv + b` divergent -> "s" constraint emitted a
// VGPR pair -> assembler error.)
// ---------------------------------------------------------------------------
#define SLOADV(V0, V1, V2, V3, P)                                             \
    {                                                                         \
        unsigned long long _a = (unsigned long long)(P);                      \
        uint_t _lo = __builtin_amdgcn_readfirstlane((uint_t)_a);              \
        uint_t _hi = __builtin_amdgcn_readfirstlane((uint_t)(_a >> 32));      \
        unsigned long long _sa = (((unsigned long long)_hi) << 32) | _lo;     \
        asm volatile("s_load_dwordx16 %0, %4, 0x0\n\t"                        \
                     "s_load_dwordx16 %1, %4, 0x40\n\t"                       \
                     "s_load_dwordx16 %2, %4, 0x80\n\t"                       \
                     "s_load_dwordx16 %3, %4, 0xC0"                           \
                     : "=&s"(V0), "=&s"(V1), "=&s"(V2), "=&s"(V3)             \
                     : "s"(_sa));                                             \
    }

#define SFENCE(V0, V1, V2, V3)                                                \
    asm volatile("s_waitcnt lgkmcnt(0)"                                       \
                 : "+s"(V0), "+s"(V1), "+s"(V2), "+s"(V3) :: "memory");       \
    __builtin_amdgcn_sched_barrier(0);

#define ISSUE8(R, J0)                                                         \
    _Pragma("unroll")                                                         \
    for (int j = 0; j < 8; j++) {                                             \
        int sc = __builtin_amdgcn_readlane(vcl, (J0) + j);                    \
        R[j] = xb[((size_t)(uint_t)sc << 6) + lane];                          \
    }

#define CONS8U(R, VV, H)                                                      \
    _Pragma("unroll")                                                         \
    for (int j = 0; j < 8; j += 2) {                                          \
        acc0 += __int_as_float(VV[(H) + j])     * __uint_as_float((uint_t)R[j] << 16);     \
        acc1 += __int_as_float(VV[(H) + j + 1]) * __uint_as_float((uint_t)R[j + 1] << 16); \
    }

#define CONS8G(R, VV, H, J0)                                                  \
    _Pragma("unroll")                                                         \
    for (int j = 0; j < 8; j += 2) {                                          \
        float s0 = ((J0) + j     < rem) ? __int_as_float(VV[(H) + j])     : 0.f; \
        float s1 = ((J0) + j + 1 < rem) ? __int_as_float(VV[(H) + j + 1]) : 0.f; \
        acc0 += s0 * __uint_as_float((uint_t)R[j] << 16);                     \
        acc1 += s1 * __uint_as_float((uint_t)R[j + 1] << 16);                 \
    }

#define CGROUP(R, VV, H, J0)                                                  \
    if (rem >= (J0) + 8) { CONS8U(R, VV, H) } else { CONS8G(R, VV, H, J0) }

__device__ __forceinline__ float spmm_row_rl(int beg, int end, int lane,
                                             const int* __restrict__ cvc,
                                             const float* __restrict__ cvv,
                                             const ushort_t* __restrict__ xb) {
    float acc0 = 0.f, acc1 = 0.f;
#pragma unroll 1
    for (int b = beg; b < end; b += 64) {
        int vc = cvc[b + lane];              // coalesced 256B, 1 vmcnt entry
        int vcl = (b + lane) < end ? vc : 0; // per-lane col clamp (1 cndmask)
        int rem = end - b;                   // wave-uniform
        if (rem > 64) rem = 64;

        i16 V0, V1, V2, V3;
        SLOADV(V0, V1, V2, V3, cvv + b)      // 64 vals -> SGPRs (SMEM pipe)

        ushort_t q0[8], q1[8], q2[8], q3[8];
        // ---- half 0: edges 0..31 ----
        ISSUE8(q0, 0)
        if (rem > 8)  { ISSUE8(q1, 8)  }
        if (rem > 16) { ISSUE8(q2, 16) }
        if (rem > 24) { ISSUE8(q3, 24) }
        SFENCE(V0, V1, V2, V3)               // vals ready; gathers in flight
        CGROUP(q0, V0, 0, 0)
        if (rem > 8)  { CGROUP(q1, V0, 8, 8)  }
        if (rem > 16) { CGROUP(q2, V1, 0, 16) }
        if (rem > 24) { CGROUP(q3, V1, 8, 24) }
        // ---- half 1: edges 32..63 ----
        if (rem > 32) {
            ISSUE8(q0, 32)
            if (rem > 40) { ISSUE8(q1, 40) }
            if (rem > 48) { ISSUE8(q2, 48) }
            if (rem > 56) { ISSUE8(q3, 56) }
            CGROUP(q0, V2, 0, 32)
            if (rem > 40) { CGROUP(q1, V2, 8, 40) }
            if (rem > 48) { CGROUP(q2, V3, 0, 48) }
            if (rem > 56) { CGROUP(q3, V3, 8, 56) }
        }
    }
    return acc0 + acc1;
}

__global__ void k_spmm(const int2* __restrict__ ranges, const int* __restrict__ cvc,
                       const float* __restrict__ cvv,
                       const ushort_t* __restrict__ xb, ushort_t* __restrict__ out) {
    int row = (blockIdx.x * blockDim.x + threadIdx.x) >> 6;
    int lane = threadIdx.x & 63;
    if (row >= N_NODES) return;
    row = __builtin_amdgcn_readfirstlane(row);
    int2 rng = ranges[row];
    int beg = __builtin_amdgcn_readfirstlane(rng.x);
    int end = __builtin_amdgcn_readfirstlane(rng.y);
    float a = spmm_row_rl(beg, end, lane, cvc, cvv, xb);
    out[(size_t)row * 64 + lane] = f32_to_bf16(a);   // 64 lanes x 2B = 128B
}

// ---------------------------------------------------------------------------
// k_last (R21b: PHI-FREE restructure). beg/end computed unconditionally with
// a clamped batch index; end collapses to beg for invalid waves INSIDE the
// final readfirstlane, so no divergent phi reaches the row loop (the R21
// compile failure). Stores still guarded by valid.
// ---------------------------------------------------------------------------
__global__ void k_last(const int2* __restrict__ ranges, const int* __restrict__ cvc,
                       const float* __restrict__ cvv,
                       const int* __restrict__ users, const int* __restrict__ items,
                       const float* __restrict__ ue, const float* __restrict__ ie,
                       const ushort_t* __restrict__ xbA, const ushort_t* __restrict__ xbB,
                       float* __restrict__ out, int batch) {
    __shared__ float uv[2][64];
    int lane  = threadIdx.x & 63;
    int lwave = threadIdx.x >> 6;            // 0..3
    int gwave = (int)blockIdx.x * 4 + lwave;
    int w     = gwave >> 1;                  // batch element
    int side  = gwave & 1;                   // 0=user, 1=item
    bool valid = w < batch;
    int wc    = valid ? w : batch - 1;       // clamped (loads always safe)

    int idxv = __builtin_amdgcn_readfirstlane(side ? items[wc] : users[wc]);
    int row  = side ? NUM_USERS + idxv : idxv;
    int2 rng = ranges[row];
    int beg  = __builtin_amdgcn_readfirstlane(rng.x);
    int end  = __builtin_amdgcn_readfirstlane(valid ? rng.y : rng.x); // invalid -> empty
    float a = spmm_row_rl(beg, end, lane, cvc, cvv, xbB);

    float e = side ? ie[(size_t)idxv * EMBED_DIM + lane]
                   : ue[(size_t)idxv * EMBED_DIM + lane];
    float A = bf16_to_f32(xbA[(size_t)row * 64 + lane]);
    float B = bf16_to_f32(xbB[(size_t)row * 64 + lane]);
    float x_ = e + A + B + a;

    int slot = lwave >> 1;                   // 0..1 (pair within block)
    if (valid && side == 0) uv[slot][lane] = x_;
    __syncthreads();
    if (valid && side == 1) {
        float p = x_ * uv[slot][lane];
#pragma unroll
        for (int d = 32; d > 0; d >>= 1) p += __shfl_down(p, d, 64);
        if (lane == 0) out[w] = p * (1.0f / 16.0f);   // 1/16 mean^2 scale
    }
}

// ---------------------------------------------------------------------------

extern "C" void kernel_launch(void* const* d_in, const int* in_sizes, int n_in,
                              void* d_out, int out_size, void* d_ws, size_t ws_size,
                              hipStream_t stream) {
    const int*   users    = (const int*)  d_in[0];
    const int*   items    = (const int*)  d_in[1];
    const int*   adj_rows = (const int*)  d_in[2];
    const int*   adj_cols = (const int*)  d_in[3];
    const float* adj_vals = (const float*)d_in[4];
    const float* user_emb = (const float*)d_in[5];
    const float* item_emb = (const float*)d_in[6];
    float* out = (float*)d_out;

    const int batch = in_sizes[0];
    const int nnz   = in_sizes[2];

    // fixed bucket capacity: mean * 9/8, rounded up to 64 (16-sigma margin)
    int cap = ((nnz / B_BUCKETS) * 9 + 7) / 8;
    cap = (cap + 63) & ~63;
    const size_t padded = (size_t)B_BUCKETS * cap;   // ~5.4M entries
    const int chunks = (cap + PLACE_CHUNK - 1) / PLACE_CHUNK;     // ~9

    char* p = (char*)d_ws;
    auto alloc = [&](size_t bytes) -> char* {
        char* r = p;
        p += (bytes + 255) & ~(size_t)255;
        return r;
    };
    const size_t xb_bytes = (size_t)N_NODES * EMBED_DIM * 2;       // 19.2 MB
    int2*     ranges = (int2*) alloc((size_t)N_NODES * 8);
    int*      cursor = (int*)  alloc(NBP * 4);
    int*      H      = (int*)  alloc((size_t)B_BUCKETS * chunks * ROWS_PER_BUCKET * 4); // 5.4 MB
    int*      cvc    = (int*)  alloc(padded * 4);                  // cols (split)
    float*    cvv    = (float*)alloc(padded * 4);                  // vals (split)
    // region overlays: staging (build) vs xbA+xbB (layer buffers)
    size_t    region_bytes = padded * 8;
    if (region_bytes < 2 * xb_bytes) region_bytes = 2 * xb_bytes;
    char*     region  = alloc(region_bytes);
    int2*     staging = (int2*)region;
    ushort_t* xbA     = (ushort_t*)region;
    ushort_t* xbB     = (ushort_t*)(region + xb_bytes);
    ushort_t* xb_ego  = (ushort_t*)alloc(xb_bytes);

    const int g_conv  = ((N_NODES * EMBED_DIM / 4) + 511) / 512;   // 4688
    const int g_bin   = (nnz + BIN_CHUNK - 1) / BIN_CHUNK;         // 2344
    const int g_nodes = (N_NODES + 3) / 4;                         // 4 waves/block
    const int g_last  = (2 * batch + 3) / 4;                       // wave pairs

    // ---- build: bin -> per-chunk hist -> scan -> place (no global atomics
    // on the edge-hot path anywhere) ----
    hipMemsetAsync(cursor, 0, NBP * 4, stream);
    k_bin2<<<g_conv + g_bin, 512, 0, stream>>>(user_emb, item_emb, xb_ego,
                                               adj_rows, adj_cols, adj_vals,
                                               cursor, staging, nnz, cap, g_conv);
    k_hist<<<B_BUCKETS * chunks, 512, 0, stream>>>(staging, cursor, H, cap, chunks);
    k_scan2<<<B_BUCKETS, 512, 0, stream>>>(H, ranges, cap, chunks);
    k_place2<<<B_BUCKETS * chunks, 512, 0, stream>>>(staging, cursor, H,
                                                     cvc, cvv, cap, chunks);

    // ---- layer 1: xbA = A * ego ----
    k_spmm<<<g_nodes, 256, 0, stream>>>(ranges, cvc, cvv, xb_ego, xbA);

    // ---- layer 2: xbB = A * xbA ----
    k_spmm<<<g_nodes, 256, 0, stream>>>(ranges, cvc, cvv, xbA, xbB);

    // ---- layer 3 (batch rows only) + gather + dot, fused ----
    k_last<<<g_last, 256, 0, stream>>>(ranges, cvc, cvv, users, items,
                                       user_emb, item_emb, xbA, xbB, out, batch);
}

// Round 12
// 420.453 us; speedup vs baseline: 1.1953x; 1.1953x over previous
//
#include <hip/hip_runtime.h>
#include <hip/hip_bf16.h>

#define NUM_USERS 100000
#define NUM_ITEMS 50000
#define EMBED_DIM 64
#define N_NODES   150000                 // NUM_USERS + NUM_ITEMS
#define ROW_SHIFT 9                      // 512 rows per bucket
#define ROWS_PER_BUCKET 512
#define B_BUCKETS ((N_NODES + ROWS_PER_BUCKET - 1) / ROWS_PER_BUCKET)   // 293
#define NBP 512                          // padded bucket-array size
#define BIN_CHUNK 2048                   // edges per bin block (4/thread @512)
#define PLACE_CHUNK 4096                 // staging entries per hist/place block (R22: 2048->4096)
#define COL_MASK 0x3FFFF                 // 18 bits for col (N_NODES < 262144)

typedef unsigned short ushort_t;
typedef unsigned int uint_t;

__device__ __forceinline__ float bf16_to_f32(ushort_t u) {
    return __uint_as_float(((unsigned)u) << 16);
}
__device__ __forceinline__ ushort_t f32_to_bf16(float f) {
    return __builtin_bit_cast(ushort_t, __float2bfloat16(f));   // RNE
}

// 512-thread (8-wave) exclusive scan via shfl_up: 2 barriers.
__device__ __forceinline__ void scan512(int c, int t, int* wsum,
                                        int* excl_out, int* total_out) {
    int lane = t & 63, wv = t >> 6;
    int x = c;
#pragma unroll
    for (int d = 1; d < 64; d <<= 1) {
        int y = __shfl_up(x, d, 64);
        if (lane >= d) x += y;
    }
    if (lane == 63) wsum[wv] = x;
    __syncthreads();
    if (t < 64) {
        int s = (lane < 8) ? wsum[lane] : 0;
#pragma unroll
        for (int d = 1; d < 8; d <<= 1) {
            int y = __shfl_up(s, d, 64);
            if (lane >= d) s += y;
        }
        if (lane < 8) wsum[lane] = s;
    }
    __syncthreads();
    int off = (wv > 0) ? wsum[wv - 1] : 0;
    *excl_out = x + off - c;
    *total_out = wsum[7];
}

// ---------------------------------------------------------------------------
// k_bin2 (UNCHANGED from R20/verified): LDS-only atomics; heterogeneous grid
// (convert + bin). 2-barrier shfl scan; cols/vals register-carried from
// pass 1. R18 LESSON: no per-edge global atomics anywhere.
// ---------------------------------------------------------------------------
__global__ void __launch_bounds__(512) k_bin2(const float* __restrict__ ue,
                                              const float* __restrict__ ie,
                                              ushort_t* __restrict__ xb,
                                              const int* __restrict__ rows,
                                              const int* __restrict__ cols,
                                              const float* __restrict__ vals,
                                              int* __restrict__ cursor,
                                              int2* __restrict__ staging,
                                              int nnz, int cap, int g_conv) {
    int t = threadIdx.x;
    if ((int)blockIdx.x < g_conv) {
        // ---- convert: fp32 ego table -> bf16 (float4 granularity) ----
        int i = blockIdx.x * 512 + t;
        const int n4 = (N_NODES * EMBED_DIM) / 4;
        if (i >= n4) return;
        const int usplit = (NUM_USERS * EMBED_DIM) / 4;
        float4 f = (i < usplit) ? ((const float4*)ue)[i] : ((const float4*)ie)[i - usplit];
        ushort4 o;
        o.x = f32_to_bf16(f.x);
        o.y = f32_to_bf16(f.y);
        o.z = f32_to_bf16(f.z);
        o.w = f32_to_bf16(f.w);
        ((ushort4*)xb)[i] = o;
        return;
    }

    // ---- binning ----
    __shared__ int  ccnt[NBP];
    __shared__ int  cpos[NBP];
    __shared__ int  gdst[NBP];
    __shared__ int  wsum[8];
    __shared__ int2 entries[BIN_CHUNK];            // 16 KB
    __shared__ ushort_t ebuck[BIN_CHUNK];          // 4 KB

    int base = (blockIdx.x - g_conv) * BIN_CHUNK;
    ccnt[t] = 0;
    __syncthreads();

    int   myrow[BIN_CHUNK / 512];
    int   mycol[BIN_CHUNK / 512];
    float myval[BIN_CHUNK / 512];
#pragma unroll
    for (int k = 0; k < BIN_CHUNK / 512; k++) {
        int idx = base + k * 512 + t;
        int r = (idx < nnz) ? rows[idx] : -1;
        myrow[k] = r;
        if (r >= 0) {
            mycol[k] = cols[idx];
            myval[k] = vals[idx];
            atomicAdd(&ccnt[r >> ROW_SHIFT], 1);
        }
    }
    __syncthreads();

    int c = ccnt[t];
    int excl, total;
    scan512(c, t, wsum, &excl, &total);            // 2 barriers
    cpos[t] = excl;
    __syncthreads();

#pragma unroll
    for (int k = 0; k < BIN_CHUNK / 512; k++) {
        int r = myrow[k];
        if (r >= 0) {
            int b = r >> ROW_SHIFT;
            int lrow = r & (ROWS_PER_BUCKET - 1);
            int slot = atomicAdd(&cpos[b], 1);
            entries[slot] = make_int2(mycol[k] | (lrow << 18), __float_as_int(myval[k]));
            ebuck[slot] = (ushort_t)b;
        }
    }
    __syncthreads();

    // reserve space in each touched bucket's fixed region
    if (t < B_BUCKETS && ccnt[t] > 0) {
        int g = atomicAdd(&cursor[t], ccnt[t]);
        gdst[t] = t * cap + g - (cpos[t] - ccnt[t]);
    }
    __syncthreads();

    for (int i = t; i < total; i += 512) {
        int eb = ebuck[i];
        int pos = gdst[eb] + i;
        if (pos < (eb + 1) * cap)                     // capacity guard (never hits)
            staging[pos] = entries[i];
    }
}

// ---------------------------------------------------------------------------
// k_hist (structure unchanged; PLACE_CHUNK=4096 halves the grid — per-block
// fixed costs amortized over 2x entries; LDS still 2 KB, occupancy intact).
// ---------------------------------------------------------------------------
__global__ void __launch_bounds__(512) k_hist(const int2* __restrict__ staging,
                                              const int* __restrict__ cursor,
                                              int* __restrict__ H,
                                              int cap, int chunks) {
    __shared__ int h[ROWS_PER_BUCKET];
    int b = blockIdx.x / chunks;
    int k = blockIdx.x - b * chunks;
    int t = threadIdx.x;
    h[t] = 0;
    __syncthreads();
    int cnt_b = cursor[b];
    if (cnt_b > cap) cnt_b = cap;
    int hi = k * PLACE_CHUNK + PLACE_CHUNK;
    if (hi > cnt_b) hi = cnt_b;
    int rbase = b * cap;
#pragma unroll 1
    for (int i = k * PLACE_CHUNK + t; i < hi; i += 512)
        atomicAdd(&h[staging[rbase + i].x >> 18], 1);
    __syncthreads();
    H[(size_t)blockIdx.x * ROWS_PER_BUCKET + t] = h[t];
}

// ---------------------------------------------------------------------------
// k_scan2 (unchanged): per-bucket scan of H -> ranges + per-(chunk,row)
// start cursors rewritten into H. chunk loop now 5 iters (was 9).
// ---------------------------------------------------------------------------
__global__ void __launch_bounds__(512) k_scan2(int* __restrict__ H,
                                               int2* __restrict__ ranges,
                                               int cap, int chunks) {
    __shared__ int wsum[8];
    int b = blockIdx.x;
    int t = threadIdx.x;
    size_t base = (size_t)b * chunks * ROWS_PER_BUCKET + t;
    int c = 0;
#pragma unroll 1
    for (int k = 0; k < chunks; k++) c += H[base + (size_t)k * ROWS_PER_BUCKET];
    int excl, total;
    scan512(c, t, wsum, &excl, &total);
    (void)total;
    int row = (b << ROW_SHIFT) + t;
    int beg = b * cap + excl;
    if (row < N_NODES) ranges[row] = make_int2(beg, beg + c);
    int s = beg;
#pragma unroll 1
    for (int k = 0; k < chunks; k++) {
        int hh = H[base + (size_t)k * ROWS_PER_BUCKET];
        H[base + (size_t)k * ROWS_PER_BUCKET] = s;
        s += hh;
    }
}

// ---------------------------------------------------------------------------
// k_place2 (REVERTED to R20: interleaved int2 cv — the R21 split-array +
// SMEM-val experiment regressed k_spmm 85->100 us via exposed s_load
// latency). LDS cursors; writes confined to per-bucket window -> L2-merged.
// ---------------------------------------------------------------------------
__global__ void __launch_bounds__(512) k_place2(const int2* __restrict__ staging,
                                                const int* __restrict__ cursor,
                                                const int* __restrict__ H,
                                                int2* __restrict__ cv,
                                                int cap, int chunks) {
    __shared__ int c[ROWS_PER_BUCKET];
    int b = blockIdx.x / chunks;
    int k = blockIdx.x - b * chunks;
    int t = threadIdx.x;
    c[t] = H[(size_t)blockIdx.x * ROWS_PER_BUCKET + t];
    __syncthreads();
    int cnt_b = cursor[b];
    if (cnt_b > cap) cnt_b = cap;
    int hi = k * PLACE_CHUNK + PLACE_CHUNK;
    if (hi > cnt_b) hi = cnt_b;
    int rbase = b * cap;
#pragma unroll 1
    for (int i = k * PLACE_CHUNK + t; i < hi; i += 512) {
        int2 e = staging[rbase + i];
        int pos = atomicAdd(&c[e.x >> 18], 1);
        cv[pos] = make_int2(e.x & COL_MASK, e.y);
    }
}

// ---------------------------------------------------------------------------
// R16/R20 readlane-broadcast SpMM row body (EXACT revert — verified 85.3 us;
// best of five structures tried: R12-pair 92, R13-split 135, R15-SMEM 90,
// R21-SMEM-val 100). One vmcnt-counted coalesced col+val load per 64 edges,
// readlane broadcast, 32-wide gather issue window, no hard scalar fences in
// the per-row critical path.
// ---------------------------------------------------------------------------
#define ISSUE8(R, J0)                                                         \
    _Pragma("unroll")                                                         \
    for (int j = 0; j < 8; j++) {                                             \
        int sc = __builtin_amdgcn_readlane(vc, (J0) + j);                     \
        R[j] = xb[((size_t)(uint_t)sc << 6) + lane];                          \
    }

#define CONS8(R, J0)                                                          \
    _Pragma("unroll")                                                         \
    for (int j = 0; j < 8; j++) {                                             \
        float sv = __uint_as_float((uint_t)__builtin_amdgcn_readlane(vv, (J0) + j)); \
        acc += sv * __uint_as_float((uint_t)R[j] << 16);                      \
    }

__device__ __forceinline__ float spmm_row_rl(int beg, int end, int lane,
                                             const int2* __restrict__ cv,
                                             const ushort_t* __restrict__ xb) {
    float acc = 0.f;
#pragma unroll 1
    for (int b = beg; b < end; b += 64) {
        int2 ed = cv[b + lane];              // coalesced 512B, 1 vmcnt entry
        bool lv = (b + lane) < end;
        int vc = lv ? ed.x : 0;              // per-lane clamp (2 cndmask)
        int vv = lv ? ed.y : 0;
        int rem = end - b;                   // wave-uniform
        if (rem > 64) rem = 64;

        ushort_t q0[8], q1[8], q2[8], q3[8];
        // ---- half 0: edges 0..31 ----
        ISSUE8(q0, 0)
        if (rem > 8)  { ISSUE8(q1, 8)  }
        if (rem > 16) { ISSUE8(q2, 16) }
        if (rem > 24) { ISSUE8(q3, 24) }
        CONS8(q0, 0)
        if (rem > 8)  { CONS8(q1, 8)  }
        if (rem > 16) { CONS8(q2, 16) }
        if (rem > 24) { CONS8(q3, 24) }
        // ---- half 1: edges 32..63 ----
        if (rem > 32) {
            ISSUE8(q0, 32)
            if (rem > 40) { ISSUE8(q1, 40) }
            if (rem > 48) { ISSUE8(q2, 48) }
            if (rem > 56) { ISSUE8(q3, 56) }
            CONS8(q0, 32)
            if (rem > 40) { CONS8(q1, 40) }
            if (rem > 48) { CONS8(q2, 48) }
            if (rem > 56) { CONS8(q3, 56) }
        }
    }
    return acc;
}

__global__ void k_spmm(const int2* __restrict__ ranges, const int2* __restrict__ cv,
                       const ushort_t* __restrict__ xb, ushort_t* __restrict__ out) {
    int row = (blockIdx.x * blockDim.x + threadIdx.x) >> 6;
    int lane = threadIdx.x & 63;
    if (row >= N_NODES) return;
    row = __builtin_amdgcn_readfirstlane(row);
    int2 rng = ranges[row];
    int beg = __builtin_amdgcn_readfirstlane(rng.x);
    int end = __builtin_amdgcn_readfirstlane(rng.y);
    float a = spmm_row_rl(beg, end, lane, cv, xb);
    out[(size_t)row * 64 + lane] = f32_to_bf16(a);   // 64 lanes x 2B = 128B
}

// ---------------------------------------------------------------------------
// k_last (R20 exact): one wave per (batch element, side); user vector
// crosses via LDS; item wave does the dot.
// ---------------------------------------------------------------------------
__global__ void k_last(const int2* __restrict__ ranges, const int2* __restrict__ cv,
                       const int* __restrict__ users, const int* __restrict__ items,
                       const float* __restrict__ ue, const float* __restrict__ ie,
                       const ushort_t* __restrict__ xbA, const ushort_t* __restrict__ xbB,
                       float* __restrict__ out, int batch) {
    __shared__ float uv[2][64];
    int lane  = threadIdx.x & 63;
    int lwave = threadIdx.x >> 6;            // 0..3
    int gwave = (int)blockIdx.x * 4 + lwave;
    int w     = gwave >> 1;                  // batch element
    int side  = gwave & 1;                   // 0=user, 1=item
    bool valid = w < batch;

    int beg = 0, end = 0, row = 0, idxv = 0;
    if (valid) {
        idxv = __builtin_amdgcn_readfirstlane(side ? items[w] : users[w]);
        row  = side ? NUM_USERS + idxv : idxv;
        int2 rng = ranges[row];
        beg = __builtin_amdgcn_readfirstlane(rng.x);
        end = __builtin_amdgcn_readfirstlane(rng.y);
    }
    float a = spmm_row_rl(beg, end, lane, cv, xbB);   // beg==end -> no work

    float x_ = 0.f;
    if (valid) {
        float e = side ? ie[(size_t)idxv * EMBED_DIM + lane]
                       : ue[(size_t)idxv * EMBED_DIM + lane];
        float A = bf16_to_f32(xbA[(size_t)row * 64 + lane]);
        float B = bf16_to_f32(xbB[(size_t)row * 64 + lane]);
        x_ = e + A + B + a;
    }
    int slot = lwave >> 1;                   // 0..1 (pair within block)
    if (valid && side == 0) uv[slot][lane] = x_;
    __syncthreads();
    if (valid && side == 1) {
        float p = x_ * uv[slot][lane];
#pragma unroll
        for (int d = 32; d > 0; d >>= 1) p += __shfl_down(p, d, 64);
        if (lane == 0) out[w] = p * (1.0f / 16.0f);   // 1/16 mean^2 scale
    }
}

// ---------------------------------------------------------------------------

extern "C" void kernel_launch(void* const* d_in, const int* in_sizes, int n_in,
                              void* d_out, int out_size, void* d_ws, size_t ws_size,
                              hipStream_t stream) {
    const int*   users    = (const int*)  d_in[0];
    const int*   items    = (const int*)  d_in[1];
    const int*   adj_rows = (const int*)  d_in[2];
    const int*   adj_cols = (const int*)  d_in[3];
    const float* adj_vals = (const float*)d_in[4];
    const float* user_emb = (const float*)d_in[5];
    const float* item_emb = (const float*)d_in[6];
    float* out = (float*)d_out;

    const int batch = in_sizes[0];
    const int nnz   = in_sizes[2];

    // fixed bucket capacity: mean * 9/8, rounded up to 64 (16-sigma margin)
    int cap = ((nnz / B_BUCKETS) * 9 + 7) / 8;
    cap = (cap + 63) & ~63;
    const size_t padded = (size_t)B_BUCKETS * cap;   // ~5.4M entries
    const int chunks = (cap + PLACE_CHUNK - 1) / PLACE_CHUNK;     // ~5

    char* p = (char*)d_ws;
    auto alloc = [&](size_t bytes) -> char* {
        char* r = p;
        p += (bytes + 255) & ~(size_t)255;
        return r;
    };
    const size_t xb_bytes = (size_t)N_NODES * EMBED_DIM * 2;       // 19.2 MB
    int2*     ranges = (int2*) alloc((size_t)N_NODES * 8);
    int*      cursor = (int*)  alloc(NBP * 4);
    int*      H      = (int*)  alloc((size_t)B_BUCKETS * chunks * ROWS_PER_BUCKET * 4); // 3.0 MB
    int2*     cv     = (int2*) alloc(padded * 8);                  // padded CSR
    // region overlays: staging (build) vs xbA+xbB (layer buffers)
    size_t    region_bytes = padded * 8;
    if (region_bytes < 2 * xb_bytes) region_bytes = 2 * xb_bytes;
    char*     region  = alloc(region_bytes);
    int2*     staging = (int2*)region;
    ushort_t* xbA     = (ushort_t*)region;
    ushort_t* xbB     = (ushort_t*)(region + xb_bytes);
    ushort_t* xb_ego  = (ushort_t*)alloc(xb_bytes);

    const int g_conv  = ((N_NODES * EMBED_DIM / 4) + 511) / 512;   // 4688
    const int g_bin   = (nnz + BIN_CHUNK - 1) / BIN_CHUNK;         // 2344
    const int g_nodes = (N_NODES + 3) / 4;                         // 4 waves/block
    const int g_last  = (2 * batch + 3) / 4;                       // wave pairs

    // ---- build: bin -> per-chunk hist -> scan -> place (no global atomics
    // on the edge-hot path anywhere) ----
    hipMemsetAsync(cursor, 0, NBP * 4, stream);
    k_bin2<<<g_conv + g_bin, 512, 0, stream>>>(user_emb, item_emb, xb_ego,
                                               adj_rows, adj_cols, adj_vals,
                                               cursor, staging, nnz, cap, g_conv);
    k_hist<<<B_BUCKETS * chunks, 512, 0, stream>>>(staging, cursor, H, cap, chunks);
    k_scan2<<<B_BUCKETS, 512, 0, stream>>>(H, ranges, cap, chunks);
    k_place2<<<B_BUCKETS * chunks, 512, 0, stream>>>(staging, cursor, H, cv,
                                                     cap, chunks);

    // ---- layer 1: xbA = A * ego ----
    k_spmm<<<g_nodes, 256, 0, stream>>>(ranges, cv, xb_ego, xbA);

    // ---- layer 2: xbB = A * xbA ----
    k_spmm<<<g_nodes, 256, 0, stream>>>(ranges, cv, xbA, xbB);

    // ---- layer 3 (batch rows only) + gather + dot, fused ----
    k_last<<<g_last, 256, 0, stream>>>(ranges, cv, users, items,
                                       user_emb, item_emb, xbA, xbB, out, batch);
}